// Round 1
// baseline (3872.149 us; speedup 1.0000x reference)
//
#include <hip/hip_runtime.h>
#include <hip/hip_bf16.h>

#define N_NODES 20000
#define N_EDGES 320000
#define D 128
#define MH 256
#define MO 128
#define XH 256
#define HH 256
#define KIN 257
#define TE 64

__device__ __forceinline__ float sigmoid_f(float z) { return 1.f / (1.f + __expf(-z)); }
__device__ __forceinline__ float silu_f(float z) { return z * sigmoid_f(z); }

// ---------------------------------------------------------------------------
// precompute: diff[e][3], d2[e], and global sum of d2 (for gnorm)
// ---------------------------------------------------------------------------
__global__ void precompute_kernel(const int* __restrict__ ei,
                                  const float* __restrict__ x,
                                  float* __restrict__ diff,
                                  float* __restrict__ d2,
                                  float* __restrict__ gsum) {
    int e = blockIdx.x * blockDim.x + threadIdx.x;
    float local = 0.f;
    if (e < N_EDGES) {
        int s = ei[e];
        int d = ei[N_EDGES + e];
        float dx = x[s * 3 + 0] - x[d * 3 + 0];
        float dy = x[s * 3 + 1] - x[d * 3 + 1];
        float dz = x[s * 3 + 2] - x[d * 3 + 2];
        diff[(size_t)e * 3 + 0] = dx;
        diff[(size_t)e * 3 + 1] = dy;
        diff[(size_t)e * 3 + 2] = dz;
        float dd = dx * dx + dy * dy + dz * dz;
        d2[e] = dd;
        local = dd;
    }
    #pragma unroll
    for (int o = 32; o > 0; o >>= 1) local += __shfl_down(local, o, 64);
    if ((threadIdx.x & 63) == 0) atomicAdd(gsum, local);
}

// ---------------------------------------------------------------------------
// first MLP layer of a branch: out256 = silu(A[64][K] @ W + bias) -> sH (bf16)
// A rows gathered: chunks 0-3 read A0[r0[e]][...], chunks 4-7 read A1[r1[e]][...]
// optional 257th feature d2 folded into the init (HAS_D2).
// thread mapping: te = tid>>4 (4 edges), tc = tid&15 (16 cols: u4*64+tc*4+j)
// ---------------------------------------------------------------------------
template <bool HAS_D2>
__device__ __forceinline__ void mlp_layer1(
    const float* __restrict__ W,     // [K(+1)][256]
    const float* __restrict__ bias,  // [256]
    const float* __restrict__ A0, const int* __restrict__ r0,
    const float* __restrict__ A1, const int* __restrict__ r1,
    const float* __restrict__ sd2,   // [64] or nullptr
    float (*sAT)[TE], float* sB, __hip_bfloat16 (*sH)[68],
    int tid, int te, int tc) {
    float acc[4][16];
    #pragma unroll
    for (int u = 0; u < 16; u++) {
        int c = (u >> 2) * 64 + tc * 4 + (u & 3);
        float v = bias[c];
        if (HAS_D2) {
            float w = W[256 * 256 + c];
            #pragma unroll
            for (int i = 0; i < 4; i++) acc[i][u] = v + sd2[te * 4 + i] * w;
        } else {
            #pragma unroll
            for (int i = 0; i < 4; i++) acc[i][u] = v;
        }
    }
    int eL = tid >> 2, p = tid & 3;
    #pragma unroll 1
    for (int chunk = 0; chunk < 8; chunk++) {
        __syncthreads();  // previous chunk's compute done before overwrite
        {
            const float* Abase = (chunk < 4) ? A0 : A1;
            const int* rr = (chunk < 4) ? r0 : r1;
            int node = rr[eL];
            int colbase = (chunk & 3) * 32 + p * 8;
            const float4* hp = (const float4*)(Abase + (size_t)node * 128 + colbase);
            float4 v0 = hp[0], v1 = hp[1];
            sAT[p * 8 + 0][eL] = v0.x; sAT[p * 8 + 1][eL] = v0.y;
            sAT[p * 8 + 2][eL] = v0.z; sAT[p * 8 + 3][eL] = v0.w;
            sAT[p * 8 + 4][eL] = v1.x; sAT[p * 8 + 5][eL] = v1.y;
            sAT[p * 8 + 6][eL] = v1.z; sAT[p * 8 + 7][eL] = v1.w;
        }
        {
            const float4* Bp = (const float4*)(W + (size_t)chunk * 32 * 256);
            float4* sBp = (float4*)sB;
            #pragma unroll
            for (int q = 0; q < 8; q++) sBp[tid + q * 256] = Bp[tid + q * 256];
        }
        __syncthreads();
        #pragma unroll 8
        for (int k = 0; k < 32; k++) {
            float4 a = *(const float4*)&sAT[k][te * 4];
            float av[4] = {a.x, a.y, a.z, a.w};
            #pragma unroll
            for (int u4 = 0; u4 < 4; u4++) {
                float4 b = *(const float4*)&sB[k * 256 + u4 * 64 + tc * 4];
                float bv[4] = {b.x, b.y, b.z, b.w};
                #pragma unroll
                for (int i = 0; i < 4; i++)
                    #pragma unroll
                    for (int j = 0; j < 4; j++)
                        acc[i][u4 * 4 + j] += av[i] * bv[j];
            }
        }
    }
    __syncthreads();
    #pragma unroll
    for (int u = 0; u < 16; u++) {
        int c = (u >> 2) * 64 + tc * 4 + (u & 3);
        #pragma unroll
        for (int i = 0; i < 4; i++)
            sH[c][te * 4 + i] = __float2bfloat16(silu_f(acc[i][u]));
    }
    __syncthreads();
}

// ---------------------------------------------------------------------------
// second MLP layer: acc[4][8] = sH(bf16 [256][64]) @ W[256][128] + bias
// ---------------------------------------------------------------------------
__device__ __forceinline__ void mlp_layer2_acc(
    const float* __restrict__ W, const float* __restrict__ bias,
    __hip_bfloat16 (*sH)[68], float* sB,
    int tid, int te, int tc, float acc[4][8]) {
    #pragma unroll
    for (int u = 0; u < 8; u++) {
        int c = (u >> 2) * 64 + tc * 4 + (u & 3);
        float v = bias[c];
        #pragma unroll
        for (int i = 0; i < 4; i++) acc[i][u] = v;
    }
    #pragma unroll 1
    for (int chunk = 0; chunk < 8; chunk++) {
        __syncthreads();
        {
            const float4* Bp = (const float4*)(W + (size_t)chunk * 32 * 128);
            float4* sBp = (float4*)sB;
            #pragma unroll
            for (int q = 0; q < 4; q++) sBp[tid + q * 256] = Bp[tid + q * 256];
        }
        __syncthreads();
        #pragma unroll 8
        for (int k = 0; k < 32; k++) {
            int kg = chunk * 32 + k;
            const __hip_bfloat162* ph = (const __hip_bfloat162*)&sH[kg][te * 4];
            __hip_bfloat162 x0 = ph[0], x1 = ph[1];
            float av[4] = {__bfloat162float(x0.x), __bfloat162float(x0.y),
                           __bfloat162float(x1.x), __bfloat162float(x1.y)};
            #pragma unroll
            for (int u4 = 0; u4 < 2; u4++) {
                float4 b = *(const float4*)&sB[k * 128 + u4 * 64 + tc * 4];
                float bv[4] = {b.x, b.y, b.z, b.w};
                #pragma unroll
                for (int i = 0; i < 4; i++)
                    #pragma unroll
                    for (int j = 0; j < 4; j++)
                        acc[i][u4 * 4 + j] += av[i] * bv[j];
            }
        }
    }
}

// ---------------------------------------------------------------------------
// fused edge kernel: m-branch (G1,G2,gate,scatter) + x-branch (G3,G4,scatter)
// ---------------------------------------------------------------------------
__global__ __launch_bounds__(256, 2) void edge_kernel(
    const int* __restrict__ ei, const float* __restrict__ h,
    const float* __restrict__ diff, const float* __restrict__ d2,
    const float* __restrict__ gsum,
    const float* __restrict__ Wm1, const float* __restrict__ bm1,
    const float* __restrict__ Wm2, const float* __restrict__ bm2,
    const float* __restrict__ Wa, const float* __restrict__ ba,
    const float* __restrict__ Wx1, const float* __restrict__ bx1,
    const float* __restrict__ Wx2, const float* __restrict__ bx2,
    float* __restrict__ agg_h, float* __restrict__ aggx) {
    __shared__ float sAT[32][TE];
    __shared__ float sB[32 * 256];
    __shared__ __hip_bfloat16 sH[256][68];
    __shared__ int ssrc[TE], sdst[TE];
    __shared__ float sd2[TE];

    int tid = threadIdx.x;
    int te = tid >> 4, tc = tid & 15;
    int e0 = blockIdx.x * TE;
    if (tid < TE) {
        ssrc[tid] = ei[e0 + tid];
        sd2[tid] = d2[e0 + tid];
    } else if (tid < 2 * TE) {
        sdst[tid - TE] = ei[N_EDGES + e0 + (tid - TE)];
    }
    __syncthreads();

    // ---- m branch ----
    mlp_layer1<true>(Wm1, bm1, h, ssrc, h, sdst, sd2, sAT, sB, sH, tid, te, tc);
    float acc[4][8];
    mlp_layer2_acc(Wm2, bm2, sH, sB, tid, te, tc, acc);
    // attention gate: s = m0 @ Wa + ba, reduce over 16 threads sharing edges
    float part[4] = {0.f, 0.f, 0.f, 0.f};
    #pragma unroll
    for (int u = 0; u < 8; u++) {
        int c = (u >> 2) * 64 + tc * 4 + (u & 3);
        float w = Wa[c];
        #pragma unroll
        for (int i = 0; i < 4; i++) part[i] += acc[i][u] * w;
    }
    #pragma unroll
    for (int m = 1; m < 16; m <<= 1) {
        #pragma unroll
        for (int i = 0; i < 4; i++) part[i] += __shfl_xor(part[i], m, 64);
    }
    float ba0 = ba[0];
    float gate[4];
    #pragma unroll
    for (int i = 0; i < 4; i++) gate[i] = sigmoid_f(part[i] + ba0);
    #pragma unroll
    for (int u = 0; u < 8; u++) {
        int c = (u >> 2) * 64 + tc * 4 + (u & 3);
        #pragma unroll
        for (int i = 0; i < 4; i++)
            atomicAdd(&agg_h[(size_t)ssrc[te * 4 + i] * MO + c], acc[i][u] * gate[i]);
    }

    // ---- x branch ----
    mlp_layer1<true>(Wx1, bx1, h, ssrc, h, sdst, sd2, sAT, sB, sH, tid, te, tc);
    __syncthreads();
    float* sWx2 = &sAT[0][0];  // 768 floats, fits in sAT (2048)
    sWx2[tid] = Wx2[tid];
    sWx2[256 + tid] = Wx2[256 + tid];
    sWx2[512 + tid] = Wx2[512 + tid];
    __syncthreads();
    int e = tid & 63, col = tid >> 6;
    float gn = sqrtf(*gsum);
    float invg = 1.f / (gn + 1.f);
    if (col < 3) {
        float accx = bx2[col];
        #pragma unroll 16
        for (int k = 0; k < 256; k++)
            accx += __bfloat162float(sH[k][e]) * sWx2[k * 3 + col];
        float df = diff[(size_t)(e0 + e) * 3 + col];
        atomicAdd(&aggx[(size_t)ssrc[e] * 3 + col], df * accx * invg);
    }
}

// ---------------------------------------------------------------------------
// fused node kernel: new_h = silu(cat(h,agg_h)@Wh1+bh1)@Wh2+bh2 ; new_x = x+aggx
// ---------------------------------------------------------------------------
__global__ __launch_bounds__(256, 2) void node_kernel(
    const float* __restrict__ hc, const float* __restrict__ xc,
    const float* __restrict__ agg_h, const float* __restrict__ aggx,
    const float* __restrict__ Wh1, const float* __restrict__ bh1,
    const float* __restrict__ Wh2, const float* __restrict__ bh2,
    float* __restrict__ ho, float* __restrict__ xo) {
    __shared__ float sAT[32][TE];
    __shared__ float sB[32 * 256];
    __shared__ __hip_bfloat16 sH[256][68];
    __shared__ int snode[TE];

    int tid = threadIdx.x;
    int te = tid >> 4, tc = tid & 15;
    int n0 = blockIdx.x * TE;
    if (tid < TE) snode[tid] = (n0 + tid < N_NODES) ? (n0 + tid) : (N_NODES - 1);
    __syncthreads();

    mlp_layer1<false>(Wh1, bh1, hc, snode, agg_h, snode, nullptr, sAT, sB, sH, tid, te, tc);
    float acc[4][8];
    mlp_layer2_acc(Wh2, bh2, sH, sB, tid, te, tc, acc);
    #pragma unroll
    for (int u = 0; u < 8; u++) {
        int c = (u >> 2) * 64 + tc * 4 + (u & 3);
        #pragma unroll
        for (int i = 0; i < 4; i++) {
            int node = n0 + te * 4 + i;
            if (node < N_NODES) ho[(size_t)node * D + c] = acc[i][u];
        }
    }
    int nn = tid & 63, col = tid >> 6;
    int node = n0 + nn;
    if (col < 3 && node < N_NODES)
        xo[(size_t)node * 3 + col] = xc[(size_t)node * 3 + col] + aggx[(size_t)node * 3 + col];
}

// ---------------------------------------------------------------------------
extern "C" void kernel_launch(void* const* d_in, const int* in_sizes, int n_in,
                              void* d_out, int out_size, void* d_ws, size_t ws_size,
                              hipStream_t stream) {
    const int* ei = (const int*)d_in[0];
    const float* h_in = (const float*)d_in[1];
    const float* x_in = (const float*)d_in[2];
    const float* Wm1 = (const float*)d_in[3];
    const float* bm1 = (const float*)d_in[4];
    const float* Wm2 = (const float*)d_in[5];
    const float* bm2 = (const float*)d_in[6];
    const float* Wx1 = (const float*)d_in[7];
    const float* bx1 = (const float*)d_in[8];
    const float* Wx2 = (const float*)d_in[9];
    const float* bx2 = (const float*)d_in[10];
    const float* Wh1 = (const float*)d_in[11];
    const float* bh1 = (const float*)d_in[12];
    const float* Wh2 = (const float*)d_in[13];
    const float* bh2 = (const float*)d_in[14];
    const float* Wa = (const float*)d_in[15];
    const float* ba = (const float*)d_in[16];

    float* ws = (float*)d_ws;
    float* h_a = ws;   ws += (size_t)N_NODES * D;
    float* x_a = ws;   ws += (size_t)N_NODES * 3;
    float* diff = ws;  ws += (size_t)N_EDGES * 3;
    float* d2 = ws;    ws += (size_t)N_EDGES;
    float* agg_h = ws; ws += (size_t)N_NODES * MO;
    float* aggx = ws;  ws += (size_t)N_NODES * 3;
    float* gsum = ws;  ws += 1;

    float* h_out_f = (float*)d_out;
    float* x_out_f = h_out_f + (size_t)N_NODES * D;

    for (int l = 0; l < 2; l++) {
        const float* hc = (l == 0) ? h_in : h_a;
        const float* xc = (l == 0) ? x_in : x_a;
        float* ho = (l == 0) ? h_a : h_out_f;
        float* xo = (l == 0) ? x_a : x_out_f;

        hipMemsetAsync(gsum, 0, sizeof(float), stream);
        hipMemsetAsync(agg_h, 0, sizeof(float) * (size_t)N_NODES * MO, stream);
        hipMemsetAsync(aggx, 0, sizeof(float) * (size_t)N_NODES * 3, stream);

        precompute_kernel<<<N_EDGES / 256, 256, 0, stream>>>(ei, xc, diff, d2, gsum);

        edge_kernel<<<N_EDGES / TE, 256, 0, stream>>>(
            ei, hc, diff, d2, gsum,
            Wm1 + (size_t)l * KIN * MH, bm1 + (size_t)l * MH,
            Wm2 + (size_t)l * MH * MO, bm2 + (size_t)l * MO,
            Wa + (size_t)l * MO, ba + l,
            Wx1 + (size_t)l * KIN * XH, bx1 + (size_t)l * XH,
            Wx2 + (size_t)l * XH * 3, bx2 + (size_t)l * 3,
            agg_h, aggx);

        node_kernel<<<(N_NODES + TE - 1) / TE, 256, 0, stream>>>(
            hc, xc, agg_h, aggx,
            Wh1 + (size_t)l * (D + MO) * HH, bh1 + (size_t)l * HH,
            Wh2 + (size_t)l * HH * D, bh2 + (size_t)l * D,
            ho, xo);
    }
}

// Round 3
// 1132.798 us; speedup vs baseline: 3.4182x; 3.4182x over previous
//
#include <hip/hip_runtime.h>
#include <hip/hip_bf16.h>

#define N_NODES 20000
#define N_EDGES 320000
#define D 128

typedef __attribute__((ext_vector_type(8))) short short8;
typedef __attribute__((ext_vector_type(4))) float f32x4;

__device__ __forceinline__ float sigmoid_f(float z) { return 1.f / (1.f + __expf(-z)); }
__device__ __forceinline__ float silu_f(float z) { return z * sigmoid_f(z); }
__device__ __forceinline__ short f2bf(float f) {
    union { float f; unsigned u; } a; a.f = f;
    unsigned r = a.u + 0x7fff + ((a.u >> 16) & 1);   // RNE
    return (short)(r >> 16);
}
__device__ __forceinline__ float bf2f(short s) {
    union { unsigned u; float f; } a; a.u = ((unsigned)(unsigned short)s) << 16;
    return a.f;
}

// ---------------------------------------------------------------------------
// gsum = sum over all edges of ||x[src]-x[dst]||^2 (for the global frobenius norm)
// ---------------------------------------------------------------------------
__global__ void precompute_kernel(const int* __restrict__ ei,
                                  const float* __restrict__ x,
                                  float* __restrict__ gsum) {
    int e = blockIdx.x * blockDim.x + threadIdx.x;
    float local = 0.f;
    if (e < N_EDGES) {
        int s = ei[e];
        int d = ei[N_EDGES + e];
        float dx = x[s * 3 + 0] - x[d * 3 + 0];
        float dy = x[s * 3 + 1] - x[d * 3 + 1];
        float dz = x[s * 3 + 2] - x[d * 3 + 2];
        local = dx * dx + dy * dy + dz * dz;
    }
    #pragma unroll
    for (int o = 32; o > 0; o >>= 1) local += __shfl_down(local, o, 64);
    if ((threadIdx.x & 63) == 0) atomicAdd(gsum, local);
}

// ---------------------------------------------------------------------------
// transpose+bf16-convert the per-layer weights.
// WcatT[1024][128]: rows 0-255 = Wm1[0:128]^T, 256-511 = Wm1[128:256]^T,
//                   512-767 = Wx1[0:128]^T, 768-1023 = Wx1[128:256]^T
// Wm2T[128][256], Wh1T[256][256], Wh2T[128][256]
// ---------------------------------------------------------------------------
__global__ void prep_weights(const float* __restrict__ Wm1, const float* __restrict__ Wx1,
                             const float* __restrict__ Wm2, const float* __restrict__ Wh1,
                             const float* __restrict__ Wh2,
                             short* __restrict__ WcatT, short* __restrict__ Wm2T,
                             short* __restrict__ Wh1T, short* __restrict__ Wh2T) {
    int idx = blockIdx.x * 256 + threadIdx.x;   // 0 .. 262143
    if (idx < 131072) {
        int seg = idx >> 15, r = idx & 32767, k = r >> 8, c = r & 255;
        const float* s = (seg == 0) ? Wm1 : (seg == 1) ? Wm1 + 128 * 256
                        : (seg == 2) ? Wx1 : Wx1 + 128 * 256;
        WcatT[(size_t)(seg * 256 + c) * 128 + k] = f2bf(s[k * 256 + c]);
    } else if (idx < 163840) {
        int r = idx - 131072, k = r >> 7, c = r & 127;
        Wm2T[c * 256 + k] = f2bf(Wm2[k * 128 + c]);
    } else if (idx < 229376) {
        int r = idx - 163840, k = r >> 8, c = r & 255;
        Wh1T[c * 256 + k] = f2bf(Wh1[k * 256 + c]);
    } else {
        int r = idx - 229376, k = r >> 7, c = r & 127;
        Wh2T[c * 256 + k] = f2bf(Wh2[k * 128 + c]);
    }
}

// ---------------------------------------------------------------------------
// T[n][1024] (bf16) = h[n][0:128] @ WcatT^T   (MFMA 16x16x32 bf16)
// grid (ceil(N/64), 4); block 256 = 4 waves; wave w: rows w*16..+15, 256 cols
// ---------------------------------------------------------------------------
__global__ __launch_bounds__(256, 4) void tgemm_kernel(const float* __restrict__ h,
        const short* __restrict__ WcatT, short* __restrict__ T) {
    int tid = threadIdx.x, w = tid >> 6, l = tid & 63;
    int l15 = l & 15, kg = l >> 4;
    int rowbase = blockIdx.x * 64 + w * 16;
    int cg = blockIdx.y;                       // 0..3
    int arow = rowbase + l15; if (arow >= N_NODES) arow = N_NODES - 1;
    f32x4 acc[16];
    #pragma unroll
    for (int ct = 0; ct < 16; ct++) acc[ct] = (f32x4){0.f, 0.f, 0.f, 0.f};
    #pragma unroll
    for (int ks = 0; ks < 4; ks++) {
        int kb = ks * 32 + kg * 8;
        const f32x4* hp = (const f32x4*)(h + (size_t)arow * 128 + kb);
        f32x4 h0 = hp[0], h1 = hp[1];
        short8 a;
        a[0] = f2bf(h0.x); a[1] = f2bf(h0.y); a[2] = f2bf(h0.z); a[3] = f2bf(h0.w);
        a[4] = f2bf(h1.x); a[5] = f2bf(h1.y); a[6] = f2bf(h1.z); a[7] = f2bf(h1.w);
        #pragma unroll
        for (int ct = 0; ct < 16; ct++) {
            short8 b = *(const short8*)(WcatT + (size_t)(cg * 256 + ct * 16 + l15) * 128 + kb);
            acc[ct] = __builtin_amdgcn_mfma_f32_16x16x32_bf16(a, b, acc[ct], 0, 0, 0);
        }
    }
    #pragma unroll
    for (int ct = 0; ct < 16; ct++) {
        #pragma unroll
        for (int r = 0; r < 4; r++) {
            int node = rowbase + kg * 4 + r;
            if (node < N_NODES)
                T[(size_t)node * 1024 + cg * 256 + ct * 16 + l15] = f2bf(acc[ct][r]);
        }
    }
}

// ---------------------------------------------------------------------------
// fused edge kernel. 64 edges/block, 4 waves, 16 edges/wave, no LDS.
// diff/d2 recomputed in-register from x (saves the diff/d2 buffers).
// z_m = T[src][0:256] + T[dst][256:512] + d2*Wm1[256] + bm1 -> silu -> MFMA @Wm2
// gate + scatter agg_h; x-branch analogous with in-register @Wx2 dot.
// ---------------------------------------------------------------------------
__global__ __launch_bounds__(256, 4) void edge_kernel(
    const int* __restrict__ ei, const short* __restrict__ T,
    const float* __restrict__ xc, const float* __restrict__ gsum,
    const float* __restrict__ Wm1r, const float* __restrict__ bm1,
    const short* __restrict__ Wm2T, const float* __restrict__ bm2,
    const float* __restrict__ Wa, const float* __restrict__ ba,
    const float* __restrict__ Wx1r, const float* __restrict__ bx1,
    const float* __restrict__ Wx2, const float* __restrict__ bx2,
    float* __restrict__ agg_h, float* __restrict__ aggx) {
    int tid = threadIdx.x, w = tid >> 6, l = tid & 63;
    int l15 = l & 15, kg = l >> 4;
    int ebase = blockIdx.x * 64 + w * 16;
    int e = ebase + l15;
    int src = ei[e], dst = ei[N_EDGES + e];
    float dfx = xc[src * 3 + 0] - xc[dst * 3 + 0];
    float dfy = xc[src * 3 + 1] - xc[dst * 3 + 1];
    float dfz = xc[src * 3 + 2] - xc[dst * 3 + 2];
    float d2v = dfx * dfx + dfy * dfy + dfz * dfz;

    // ---- m branch ----
    f32x4 acc[8];
    #pragma unroll
    for (int ct = 0; ct < 8; ct++) { float bv = bm2[ct * 16 + l15]; acc[ct] = (f32x4){bv, bv, bv, bv}; }
    #pragma unroll
    for (int ks = 0; ks < 8; ks++) {
        int cb = ks * 32 + kg * 8;
        short8 ts = *(const short8*)(T + (size_t)src * 1024 + cb);
        short8 td = *(const short8*)(T + (size_t)dst * 1024 + 256 + cb);
        f32x4 w0 = ((const f32x4*)(Wm1r + cb))[0], w1 = ((const f32x4*)(Wm1r + cb))[1];
        f32x4 b0 = ((const f32x4*)(bm1 + cb))[0], b1 = ((const f32x4*)(bm1 + cb))[1];
        float wv[8], bv[8];
        *(f32x4*)&wv[0] = w0; *(f32x4*)&wv[4] = w1;
        *(f32x4*)&bv[0] = b0; *(f32x4*)&bv[4] = b1;
        short8 a;
        #pragma unroll
        for (int i = 0; i < 8; i++) {
            float z = bf2f(ts[i]) + bf2f(td[i]) + d2v * wv[i] + bv[i];
            a[i] = f2bf(silu_f(z));
        }
        #pragma unroll
        for (int ct = 0; ct < 8; ct++) {
            short8 b = *(const short8*)(Wm2T + (size_t)(ct * 16 + l15) * 256 + cb);
            acc[ct] = __builtin_amdgcn_mfma_f32_16x16x32_bf16(a, b, acc[ct], 0, 0, 0);
        }
    }
    // gate: s = m @ Wa + ba (reduce cols: in-lane over ct, shfl over l&15)
    float part[4] = {0.f, 0.f, 0.f, 0.f};
    #pragma unroll
    for (int ct = 0; ct < 8; ct++) {
        float wa = Wa[ct * 16 + l15];
        #pragma unroll
        for (int r = 0; r < 4; r++) part[r] += acc[ct][r] * wa;
    }
    #pragma unroll
    for (int m = 1; m < 16; m <<= 1) {
        #pragma unroll
        for (int r = 0; r < 4; r++) part[r] += __shfl_xor(part[r], m, 64);
    }
    float ba0 = ba[0];
    float gate[4];
    int srow[4];
    #pragma unroll
    for (int r = 0; r < 4; r++) {
        gate[r] = sigmoid_f(part[r] + ba0);
        srow[r] = ei[ebase + kg * 4 + r];
    }
    #pragma unroll
    for (int ct = 0; ct < 8; ct++)
        #pragma unroll
        for (int r = 0; r < 4; r++)
            atomicAdd(&agg_h[(size_t)srow[r] * 128 + ct * 16 + l15], acc[ct][r] * gate[r]);

    // ---- x branch ----
    float px[3] = {0.f, 0.f, 0.f};
    #pragma unroll
    for (int ks = 0; ks < 8; ks++) {
        int cb = ks * 32 + kg * 8;
        short8 ts = *(const short8*)(T + (size_t)src * 1024 + 512 + cb);
        short8 td = *(const short8*)(T + (size_t)dst * 1024 + 768 + cb);
        f32x4 w0 = ((const f32x4*)(Wx1r + cb))[0], w1 = ((const f32x4*)(Wx1r + cb))[1];
        f32x4 b0 = ((const f32x4*)(bx1 + cb))[0], b1 = ((const f32x4*)(bx1 + cb))[1];
        float wv[8], bv[8];
        *(f32x4*)&wv[0] = w0; *(f32x4*)&wv[4] = w1;
        *(f32x4*)&bv[0] = b0; *(f32x4*)&bv[4] = b1;
        float wx[24];
        const f32x4* xp = (const f32x4*)(Wx2 + cb * 3);
        #pragma unroll
        for (int q = 0; q < 6; q++) *(f32x4*)&wx[q * 4] = xp[q];
        #pragma unroll
        for (int i = 0; i < 8; i++) {
            float z = silu_f(bf2f(ts[i]) + bf2f(td[i]) + d2v * wv[i] + bv[i]);
            px[0] += z * wx[i * 3 + 0];
            px[1] += z * wx[i * 3 + 1];
            px[2] += z * wx[i * 3 + 2];
        }
    }
    #pragma unroll
    for (int m = 16; m < 64; m <<= 1) {
        #pragma unroll
        for (int c = 0; c < 3; c++) px[c] += __shfl_xor(px[c], m, 64);
    }
    if (kg == 0) {
        float gn = sqrtf(gsum[0]);
        float invg = 1.f / (gn + 1.f);
        float df[3] = {dfx, dfy, dfz};
        #pragma unroll
        for (int c = 0; c < 3; c++) {
            float mx = px[c] + bx2[c];
            float xm = df[c] * mx * invg;
            atomicAdd(&aggx[(size_t)src * 3 + c], xm);
        }
    }
}

// ---------------------------------------------------------------------------
// node kernel (MFMA): new_h = silu(cat(h,agg)@Wh1+bh1)@Wh2+bh2 ; new_x = x+aggx
// 64 nodes/block, 4 waves. ho/xo may alias hc/xc (wave-local rows, read-before-write).
// ---------------------------------------------------------------------------
__global__ __launch_bounds__(256, 4) void node_kernel(
    const float* __restrict__ hc, const float* __restrict__ xc,
    const float* __restrict__ agg_h, const float* __restrict__ aggx,
    const short* __restrict__ Wh1T, const float* __restrict__ bh1,
    const short* __restrict__ Wh2T, const float* __restrict__ bh2,
    float* __restrict__ ho, float* __restrict__ xo) {
    __shared__ short sH[64][264];
    int tid = threadIdx.x, w = tid >> 6, l = tid & 63;
    int l15 = l & 15, kg = l >> 4;
    int nbase = blockIdx.x * 64;
    int arow = nbase + w * 16 + l15;
    int arc = (arow < N_NODES) ? arow : (N_NODES - 1);

    f32x4 acc1[16];
    #pragma unroll
    for (int ct = 0; ct < 16; ct++) { float bv = bh1[ct * 16 + l15]; acc1[ct] = (f32x4){bv, bv, bv, bv}; }
    #pragma unroll
    for (int ks = 0; ks < 8; ks++) {
        int kb = ks * 32 + kg * 8;
        const float* sp = (kb < 128) ? (hc + (size_t)arc * 128 + kb)
                                     : (agg_h + (size_t)arc * 128 + (kb - 128));
        f32x4 h0 = ((const f32x4*)sp)[0], h1 = ((const f32x4*)sp)[1];
        short8 a;
        a[0] = f2bf(h0.x); a[1] = f2bf(h0.y); a[2] = f2bf(h0.z); a[3] = f2bf(h0.w);
        a[4] = f2bf(h1.x); a[5] = f2bf(h1.y); a[6] = f2bf(h1.z); a[7] = f2bf(h1.w);
        #pragma unroll
        for (int ct = 0; ct < 16; ct++) {
            short8 b = *(const short8*)(Wh1T + (size_t)(ct * 16 + l15) * 256 + kb);
            acc1[ct] = __builtin_amdgcn_mfma_f32_16x16x32_bf16(a, b, acc1[ct], 0, 0, 0);
        }
    }
    #pragma unroll
    for (int ct = 0; ct < 16; ct++)
        #pragma unroll
        for (int r = 0; r < 4; r++)
            sH[w * 16 + kg * 4 + r][ct * 16 + l15] = f2bf(silu_f(acc1[ct][r]));
    __syncthreads();

    f32x4 acc2[8];
    #pragma unroll
    for (int ct = 0; ct < 8; ct++) { float bv = bh2[ct * 16 + l15]; acc2[ct] = (f32x4){bv, bv, bv, bv}; }
    #pragma unroll
    for (int ks = 0; ks < 8; ks++) {
        int kb = ks * 32 + kg * 8;
        short8 a = *(const short8*)&sH[w * 16 + l15][kb];
        #pragma unroll
        for (int ct = 0; ct < 8; ct++) {
            short8 b = *(const short8*)(Wh2T + (size_t)(ct * 16 + l15) * 256 + kb);
            acc2[ct] = __builtin_amdgcn_mfma_f32_16x16x32_bf16(a, b, acc2[ct], 0, 0, 0);
        }
    }
    #pragma unroll
    for (int ct = 0; ct < 8; ct++)
        #pragma unroll
        for (int r = 0; r < 4; r++) {
            int node = nbase + w * 16 + kg * 4 + r;
            if (node < N_NODES) ho[(size_t)node * 128 + ct * 16 + l15] = acc2[ct][r];
        }

    if (tid < 192) {
        int nn = tid / 3, c = tid - nn * 3;
        int node = nbase + nn;
        if (node < N_NODES)
            xo[(size_t)node * 3 + c] = xc[(size_t)node * 3 + c] + aggx[(size_t)node * 3 + c];
    }
}

// ---------------------------------------------------------------------------
extern "C" void kernel_launch(void* const* d_in, const int* in_sizes, int n_in,
                              void* d_out, int out_size, void* d_ws, size_t ws_size,
                              hipStream_t stream) {
    const int* ei = (const int*)d_in[0];
    const float* h_in = (const float*)d_in[1];
    const float* x_in = (const float*)d_in[2];
    const float* Wm1 = (const float*)d_in[3];
    const float* bm1 = (const float*)d_in[4];
    const float* Wm2 = (const float*)d_in[5];
    const float* bm2 = (const float*)d_in[6];
    const float* Wx1 = (const float*)d_in[7];
    const float* bx1 = (const float*)d_in[8];
    const float* Wx2 = (const float*)d_in[9];
    const float* bx2 = (const float*)d_in[10];
    const float* Wh1 = (const float*)d_in[11];
    const float* bh1 = (const float*)d_in[12];
    const float* Wh2 = (const float*)d_in[13];
    const float* bh2 = (const float*)d_in[14];
    const float* Wa = (const float*)d_in[15];
    const float* ba = (const float*)d_in[16];

    // workspace: ~49.6 MiB total (round-2's 64.4 MiB overflowed a 64 MiB ws)
    char* wsb = (char*)d_ws;
    short* T     = (short*)wsb;                 wsb += (size_t)N_NODES * 1024 * 2;
    short* WcatT = (short*)wsb;                 wsb += (size_t)1024 * 128 * 2;
    short* Wm2T  = (short*)wsb;                 wsb += (size_t)128 * 256 * 2;
    short* Wh1T  = (short*)wsb;                 wsb += (size_t)256 * 256 * 2;
    short* Wh2T  = (short*)wsb;                 wsb += (size_t)128 * 256 * 2;
    float* agg_h = (float*)wsb;                 wsb += (size_t)N_NODES * 128 * 4;
    float* aggx  = (float*)wsb;                 wsb += (size_t)N_NODES * 3 * 4;
    float* gsum  = (float*)wsb;                 wsb += 16;

    float* h_out_f = (float*)d_out;
    float* x_out_f = h_out_f + (size_t)N_NODES * D;

    for (int l = 0; l < 2; l++) {
        const float* hc = (l == 0) ? h_in : h_out_f;   // layer-0 output staged in d_out
        const float* xc = (l == 0) ? x_in : x_out_f;
        float* ho = h_out_f;
        float* xo = x_out_f;

        const float* Wm1_l = Wm1 + (size_t)l * 257 * 256;
        const float* Wx1_l = Wx1 + (size_t)l * 257 * 256;

        hipMemsetAsync(gsum, 0, sizeof(float), stream);
        hipMemsetAsync(agg_h, 0, sizeof(float) * (size_t)N_NODES * 128, stream);
        hipMemsetAsync(aggx, 0, sizeof(float) * (size_t)N_NODES * 3, stream);

        prep_weights<<<1024, 256, 0, stream>>>(
            Wm1_l, Wx1_l, Wm2 + (size_t)l * 256 * 128,
            Wh1 + (size_t)l * 256 * 256, Wh2 + (size_t)l * 256 * 128,
            WcatT, Wm2T, Wh1T, Wh2T);

        precompute_kernel<<<(N_EDGES + 255) / 256, 256, 0, stream>>>(ei, xc, gsum);

        tgemm_kernel<<<dim3((N_NODES + 63) / 64, 4), 256, 0, stream>>>(hc, WcatT, T);

        edge_kernel<<<N_EDGES / 64, 256, 0, stream>>>(
            ei, T, xc, gsum,
            Wm1_l + 256 * 256, bm1 + (size_t)l * 256,
            Wm2T, bm2 + (size_t)l * 128,
            Wa + (size_t)l * 128, ba + l,
            Wx1_l + 256 * 256, bx1 + (size_t)l * 256,
            Wx2 + (size_t)l * 256 * 3, bx2 + (size_t)l * 3,
            agg_h, aggx);

        node_kernel<<<(N_NODES + 63) / 64, 256, 0, stream>>>(
            hc, xc, agg_h, aggx,
            Wh1T, bh1 + (size_t)l * 256,
            Wh2T, bh2 + (size_t)l * 128,
            ho, xo);
    }
}